// Round 13
// baseline (155.809 us; speedup 1.0000x reference)
//
#include <hip/hip_runtime.h>
#include <cstdint>

#define TT 2048
#define NH 16
#define NKV 8
#define HD 128
// 1/sqrt(128) * log2(e)  (softmax computed in exp2 domain)
#define SCALE_L2E 0.12751743f
// static softmax max bound: ||q||=||k||=sqrt(128) (unit rmsnorm weights), RoPE is a
// rotation => |score|*log2(e) <= sqrt(128)*log2(e) = 16.33; margin -> 16.5. P in (0,1].
#define SM_M2 16.5f

typedef unsigned short u16;
typedef unsigned int u32;
typedef u16 u16x8 __attribute__((ext_vector_type(8)));
typedef u32 u32x4 __attribute__((ext_vector_type(4)));
typedef __bf16 bf16x8 __attribute__((ext_vector_type(8)));
typedef float f32x4 __attribute__((ext_vector_type(4)));
typedef float f32x16 __attribute__((ext_vector_type(16)));

__device__ inline u16 f2bf(float x){
  u32 u = __builtin_bit_cast(u32, x);
  u = (u + 0x7fffu + ((u >> 16) & 1u)) >> 16;
  return (u16)u;
}
__device__ inline float bf2f(u16 h){
  return __builtin_bit_cast(float, (u32)h << 16);
}
__device__ inline bf16x8 as_bf(u16x8 v){ return __builtin_bit_cast(bf16x8, v); }

__device__ inline void gl_lds16(const void* g, void* l){
  typedef __attribute__((address_space(1))) const void gv_t;
  typedef __attribute__((address_space(3))) void lv_t;
  __builtin_amdgcn_global_load_lds((gv_t*)g, (lv_t*)l, 16, 0, 0);
}

// ---------------- cast fp32 -> bf16 ----------------
__global__ void cast_f32_bf16(const float* __restrict__ in, u16* __restrict__ out, int n8){
  int i = blockIdx.x * blockDim.x + threadIdx.x;
  if (i < n8){
    const float4* p = (const float4*)(in + (size_t)i * 8);
    float4 a = p[0], b = p[1];
    u16x8 o = { f2bf(a.x), f2bf(a.y), f2bf(a.z), f2bf(a.w),
                f2bf(b.x), f2bf(b.y), f2bf(b.z), f2bf(b.w) };
    *(u16x8*)(out + (size_t)i * 8) = o;
  }
}

// ---------------- transpose + cast: in [R][C] f32 -> out [C][R] bf16 ----------------
__global__ void transpose_cast(const float* __restrict__ in, u16* __restrict__ out, int R, int C){
  __shared__ float tile[64][65];
  int bx = blockIdx.x * 64;  // col base (source)
  int by = blockIdx.y * 64;  // row base (source)
  int tid = threadIdx.x;
  #pragma unroll
  for (int i = 0; i < 4; ++i){
    int idx = i * 256 + tid;           // 0..1023
    int r = idx >> 4, c4 = (idx & 15) * 4;
    float4 v = *(const float4*)&in[(size_t)(by + r) * C + bx + c4];
    tile[r][c4] = v.x; tile[r][c4 + 1] = v.y; tile[r][c4 + 2] = v.z; tile[r][c4 + 3] = v.w;
  }
  __syncthreads();
  #pragma unroll
  for (int i = 0; i < 2; ++i){
    int idx = i * 256 + tid;           // 0..511
    int cc = idx >> 3, s8 = (idx & 7) * 8;
    u16x8 o;
    #pragma unroll
    for (int j = 0; j < 8; ++j) o[j] = f2bf(tile[s8 + j][cc]);
    *(u16x8*)&out[(size_t)(bx + cc) * R + by + s8] = o;
  }
}

// ---------------- lookahead-pipelined GEMM: C[M,N] = A[M,K] * B^T ----------------
template<bool F32OUT>
__global__ __launch_bounds__(512, 2) void gemm8p(const u16* __restrict__ A, const u16* __restrict__ B,
                                                 void* __restrict__ Cv, int Klen,
                                                 int lda, int ldb, int ldc, size_t zstride){
  extern __shared__ u16 smem[];     // 3 bufs x (A 128*64 + B 256*64) u16
  const int tid = threadIdx.x;
  const int wv = tid >> 6, ln = tid & 63;
  const int lg = ln >> 4, l15 = ln & 15;
  const int wr = wv >> 2, wc = wv & 3;          // 2 x 4 wave grid
  const int nbx = gridDim.x;
  const int orig = blockIdx.x + nbx * blockIdx.y;
  const int cpx = (nbx * gridDim.y) >> 3;
  const int swz = (orig & 7) * cpx + (orig >> 3);
  const int m0 = (swz / nbx) * 128, n0 = (swz % nbx) * 256;
  const int Kofs = blockIdx.z * Klen;
  const u16* Ab0 = A + (size_t)m0 * lda + Kofs;
  const u16* Bb0 = B + (size_t)n0 * ldb + Kofs;
  f32x4 acc[4][4] = {};

  auto stage = [&](int sbuf, int kt, int part){
    u16* base = smem + sbuf * 24576;
    if (part == 0){
      const u16* Ak = Ab0 + kt * 64;
      #pragma unroll
      for (int it = 0; it < 2; ++it){
        int idx = it * 512 + tid;
        int r = idx >> 3, sl = idx & 7, g = sl ^ (r & 7);
        gl_lds16(Ak + (size_t)r * lda + g * 8, base + (it * 512 + wv * 64) * 8);
      }
      const u16* Bk = Bb0 + kt * 64;
      { int idx = tid; int r = idx >> 3, sl = idx & 7, g = sl ^ (r & 7);
        gl_lds16(Bk + (size_t)r * ldb + g * 8, base + (8192 + wv * 64 * 8)); }
    } else {
      const u16* Bk = Bb0 + kt * 64;
      #pragma unroll
      for (int it = 1; it < 4; ++it){
        int idx = it * 512 + tid;
        int r = idx >> 3, sl = idx & 7, g = sl ^ (r & 7);
        gl_lds16(Bk + (size_t)r * ldb + g * 8, base + (8192 + (it * 512 + wv * 64) * 8));
      }
    }
  };

  bf16x8 a0[4], b0[4], a1[4], b1[4];
  auto ldfrags = [&](const u16* lA, bf16x8* af, bf16x8* bf, int kk){
    const u16* lB = lA + 8192;
    #pragma unroll
    for (int mm = 0; mm < 4; mm++){
      int ra = wr * 64 + mm * 16 + l15;
      int sl = (kk * 4 + lg) ^ (ra & 7);
      af[mm] = as_bf(*(const u16x8*)&lA[(ra * 8 + sl) * 8]);
    }
    #pragma unroll
    for (int nn = 0; nn < 4; nn++){
      int cb = wc * 64 + nn * 16 + l15;
      int sl = (kk * 4 + lg) ^ (cb & 7);
      bf[nn] = as_bf(*(const u16x8*)&lB[(cb * 8 + sl) * 8]);
    }
  };
  auto mfma16 = [&](bf16x8* af, bf16x8* bf){
    __builtin_amdgcn_s_setprio(1);
    #pragma unroll
    for (int mm = 0; mm < 4; mm++)
      #pragma unroll
      for (int nn = 0; nn < 4; nn++)
        acc[mm][nn] = __builtin_amdgcn_mfma_f32_16x16x32_bf16(af[mm], bf[nn], acc[mm][nn], 0, 0, 0);
    __builtin_amdgcn_s_setprio(0);
  };

  const int nk = Klen / 64;
  stage(0, 0, 0); stage(0, 0, 1);
  stage(1, 1, 0); stage(1, 1, 1);
  asm volatile("s_waitcnt vmcnt(6)" ::: "memory");
  asm volatile("s_barrier" ::: "memory");
  ldfrags(smem, a0, b0, 0);

  for (int kt = 0; kt < nk; ++kt){
    const u16* lA = smem + (kt % 3) * 24576;
    ldfrags(lA, a1, b1, 1);
    if (kt + 2 < nk) stage((kt + 2) % 3, kt + 2, 0);
    mfma16(a0, b0);
    if (kt + 2 < nk)      asm volatile("s_waitcnt vmcnt(3)" ::: "memory");
    else if (kt + 1 < nk) asm volatile("s_waitcnt vmcnt(0)" ::: "memory");
    asm volatile("s_barrier" ::: "memory");
    if (kt + 1 < nk)
      ldfrags(smem + ((kt + 1) % 3) * 24576, a0, b0, 0);
    if (kt + 2 < nk) stage((kt + 2) % 3, kt + 2, 1);
    mfma16(a1, b1);
    asm volatile("s_barrier" ::: "memory");
  }
  #pragma unroll
  for (int mm = 0; mm < 4; mm++)
    #pragma unroll
    for (int nn = 0; nn < 4; nn++){
      int grow0 = m0 + wr * 64 + mm * 16 + lg * 4;
      int gcol  = n0 + wc * 64 + nn * 16 + l15;
      #pragma unroll
      for (int r = 0; r < 4; r++){
        float v = acc[mm][nn][r];
        if (F32OUT) ((float*)Cv + blockIdx.z * zstride)[(size_t)(grow0 + r) * ldc + gcol] = v;
        else        ((u16*)Cv)[(size_t)(grow0 + r) * ldc + gcol] = f2bf(v);
      }
    }
}

// ---------------- fp32 add (split-K reduce) ----------------
__global__ void add_f32(const float* __restrict__ a, const float* __restrict__ b,
                        float* __restrict__ o, int n4){
  int i = blockIdx.x * blockDim.x + threadIdx.x;
  if (i < n4){
    float4 x = ((const float4*)a)[i], y = ((const float4*)b)[i];
    float4 z = { x.x + y.x, x.y + y.y, x.z + y.z, x.w + y.w };
    ((float4*)o)[i] = z;
  }
}

// ---------------- RMSNorm + RoPE for Q and K; one wave per (token, head-slot) ----------------
__global__ void rmsnorm_rope(const u16* __restrict__ QKV, const int* __restrict__ pos,
                             const float* __restrict__ qw, const float* __restrict__ kw,
                             u16* __restrict__ Qr, u16* __restrict__ Kr){
  int gw = (blockIdx.x * blockDim.x + threadIdx.x) >> 6;
  int ln = threadIdx.x & 63;
  int t = gw / 24, idx = gw % 24;         // 16 Q heads + 8 K heads
  if (t >= TT) return;
  bool isq = idx < NH;
  int head = isq ? idx : idx - NH;
  const u16* src = QKV + (size_t)t * 4096 + (isq ? head * HD : 2048 + head * HD);
  const float* wgt = isq ? qw : kw;
  float x0 = bf2f(src[ln]), x1 = bf2f(src[ln + 64]);
  float ss = x0 * x0 + x1 * x1;
  #pragma unroll
  for (int off = 32; off; off >>= 1) ss += __shfl_xor(ss, off);
  float r = rsqrtf(ss * (1.0f / 128.0f) + 1e-6f);
  float xn0 = x0 * r * wgt[ln], xn1 = x1 * r * wgt[ln + 64];
  float inv = exp2f(-(float)ln * 0.311430758895690f);  // log2(1e6)/64
  float ang = (float)pos[t] * inv;
  float c = cosf(ang), s = sinf(ang);
  float o0 = xn0 * c - xn1 * s;
  float o1 = xn1 * c + xn0 * s;
  u16* dst = isq ? (Qr + (size_t)t * 2048 + head * HD) : (Kr + (size_t)t * 1024 + head * HD);
  dst[ln]      = f2bf(o0);
  dst[ln + 64] = f2bf(o1);
}

// ---------------- V transpose: QKV[t][3072 + kh*128 + d] -> Vt[kh][d][t] ----------------
__global__ void v_transpose(const u16* __restrict__ QKV, u16* __restrict__ Vt){
  __shared__ u16 tile[64][72];
  int kh = blockIdx.z;
  int d0 = blockIdx.y * 64;
  int t0 = blockIdx.x * 64;
  int tid = threadIdx.x;
  #pragma unroll
  for (int it = 0; it < 2; ++it){
    int idx = it * 256 + tid;          // 0..511
    int tr = idx >> 3, seg = idx & 7;
    *(u16x8*)&tile[tr][seg * 8] =
      *(const u16x8*)(QKV + (size_t)(t0 + tr) * 4096 + 3072 + kh * HD + d0 + seg * 8);
  }
  __syncthreads();
  #pragma unroll
  for (int it = 0; it < 2; ++it){
    int idx = it * 256 + tid;
    int dr = idx >> 3, seg = idx & 7;
    u16x8 v;
    #pragma unroll
    for (int j = 0; j < 8; j++) v[j] = tile[seg * 8 + j][dr];
    *(u16x8*)(Vt + ((size_t)kh * HD + d0 + dr) * 2048 + t0 + seg * 8) = v;
  }
}

// ---------------- causal GQA flash attention: P fully in registers ----------------
// 512 blocks x 256 threads (4 waves): wave (qw = wv&1, tp = wv>>1) handles q rows
// [64qc+32qw,+32) x token half [32tp,+32) of each staged 64-token tile. Swapped QK^T
// (mfma(K,Q)) puts S[q=q5][t] lane-local in q; the PV A-fragment P[q=q5][t=8hb+j] is
// rebuilt IN REGISTERS via 8x v_cvt_pk_bf16_f32 + 4x v_permlane32_swap_b32 (the
// missing t-halves live in the partner lane l+-32 at the same q5). P never touches
// LDS; no producer/consumer roles; ONE barrier per iteration (K/V staging only).
// PV = mfma(P_A, V_B) with V-frag read from Vt tile; output C-layout identical to
// R12's acc => same tp-combine epilogue. Static-max softmax => tp partials additive.
// LDS = K dbuf 32KB + V dbuf 32KB = 64KB => 2 blocks/CU (8 waves/CU).
__global__ __launch_bounds__(256, 2) void attn(const u16* __restrict__ Qr, const u16* __restrict__ Kr,
                                               const u16* __restrict__ Vt, u16* __restrict__ O){
  extern __shared__ u16 smem[];
  u16* Karea = smem;                   // [2][64tok*128d] u16
  u16* Varea = smem + 16384;           // [2][128d*64tok] u16
  const int h = blockIdx.y, kh = h >> 1;
  const int qc = (h < 8) ? blockIdx.x : 31 - blockIdx.x;
  const int tid = threadIdx.x, wv = tid >> 6, ln = tid & 63;
  const int qw = wv & 1, tp = wv >> 1;
  const int q5 = ln & 31, hb = ln >> 5;
  const int nit = qc + 1;

  auto stage = [&](int i){
    if (i < nit){
      u16* Kd = Karea + (i & 1) * 8192;
      #pragma unroll
      for (int j = 0; j < 4; ++j){
        int lin = j * 256 + tid;
        int tok = lin >> 4, seg = lin & 15;
        gl_lds16(Kr + (size_t)(i * 64 + tok) * 1024 + kh * HD + (seg ^ (tok & 7)) * 8,
                 Kd + (j * 256 + wv * 64) * 8);
      }
      u16* Vd = Varea + (i & 1) * 8192;
      #pragma unroll
      for (int j = 0; j < 4; ++j){
        int lin = j * 256 + tid;
        int d = lin >> 3, sl = lin & 7;
        gl_lds16(Vt + (size_t)kh * HD * 2048 + (size_t)d * 2048 + i * 64 + (sl ^ (d & 7)) * 8,
                 Vd + (j * 256 + wv * 64) * 8);
      }
    }
  };

  // Q fragments: B-operand, lane holds Q[q=q5][k = 16s + 8hb + j]
  bf16x8 qf[8];
  {
    const u16* qp = Qr + (size_t)(qc * 64 + qw * 32 + q5) * 2048 + h * HD + hb * 8;
    #pragma unroll
    for (int s = 0; s < 8; ++s) qf[s] = as_bf(*(const u16x8*)(qp + s * 16));
  }
  const u16x8 ones_u = {0x3f80, 0x3f80, 0x3f80, 0x3f80, 0x3f80, 0x3f80, 0x3f80, 0x3f80};
  const bf16x8 onesf = as_bf(ones_u);

  f32x16 acc[4] = {};   // O[q(r,hb)][d = 32dblk + q5]
  f32x16 asum = {};     // row sums (via ones-B MFMA)

  stage(0);
  for (int i = 0; i < nit; ++i){
    __syncthreads();                     // buf i&1 staged; prev reads of buf (i+1)&1 done
    stage(i + 1);
    const int D0 = (i * 64 + 32 * tp) - (qc * 64 + 32 * qw);
    if (D0 <= 0){
      const u16* Kb = Karea + (i & 1) * 8192;
      const u16* Vb = Varea + (i & 1) * 8192;
      const int tokIdx = 32 * tp + q5;
      // ---- QK^T: two independent 4-MFMA chains; c[r] = S[q=q5][t=(r&3)+8(r>>2)+4hb] ----
      f32x16 ca = {}, cb = {};
      __builtin_amdgcn_s_setprio(1);
      #pragma unroll
      for (int s = 0; s < 4; ++s){
        int seg = (2 * s + hb) ^ (q5 & 7);
        bf16x8 kf = as_bf(*(const u16x8*)&Kb[tokIdx * 128 + seg * 8]);
        ca = __builtin_amdgcn_mfma_f32_32x32x16_bf16(kf, qf[s], ca, 0, 0, 0);
      }
      #pragma unroll
      for (int s = 4; s < 8; ++s){
        int seg = (2 * s + hb) ^ (q5 & 7);
        bf16x8 kf = as_bf(*(const u16x8*)&Kb[tokIdx * 128 + seg * 8]);
        cb = __builtin_amdgcn_mfma_f32_32x32x16_bf16(kf, qf[s], cb, 0, 0, 0);
      }
      __builtin_amdgcn_s_setprio(0);
      f32x16 c = ca + cb;
      const bool diag = (D0 == 0);
      // ---- P = exp2(c*scale - M2) packed to bf16 pairs (t ascending per hb) ----
      u32 pk[8];
      #pragma unroll
      for (int j = 0; j < 8; ++j){
        float pv[2];
        #pragma unroll
        for (int e = 0; e < 2; ++e){
          int r = 2 * j + e;
          int tok = (r & 3) + 8 * (r >> 2) + 4 * hb;   // local t within 32-tok subtile
          float x = c[r] * SCALE_L2E - SM_M2;
          if (diag && tok > q5) x = -1e30f;            // causal mask (local compare)
          pv[e] = exp2f(x);
        }
        asm("v_cvt_pk_bf16_f32 %0, %1, %2" : "=v"(pk[j]) : "v"(pv[0]), "v"(pv[1]));
      }
      // ---- in-register transpose of the hb-halves: 4x permlane32_swap ----
      // After swaps, frag ks0 = {pk0,pk1,pk2,pk3} holds P[q5][t = 8hb+0..7],
      //              frag ks1 = {pk4,pk5,pk6,pk7} holds P[q5][t = 16+8hb+0..7].
      asm("v_permlane32_swap_b32 %0, %1" : "+v"(pk[0]), "+v"(pk[2]));
      asm("v_permlane32_swap_b32 %0, %1" : "+v"(pk[1]), "+v"(pk[3]));
      asm("v_permlane32_swap_b32 %0, %1" : "+v"(pk[4]), "+v"(pk[6]));
      asm("v_permlane32_swap_b32 %0, %1" : "+v"(pk[5]), "+v"(pk[7]));
      bf16x8 pa0 = __builtin_bit_cast(bf16x8, u32x4{pk[0], pk[1], pk[2], pk[3]});
      bf16x8 pa1 = __builtin_bit_cast(bf16x8, u32x4{pk[4], pk[5], pk[6], pk[7]});
      // ---- PV (+ row-sum): O += P * V, ks in {0,1} covers the 32 tokens ----
      __builtin_amdgcn_s_setprio(1);
      asum = __builtin_amdgcn_mfma_f32_32x32x16_bf16(pa0, onesf, asum, 0, 0, 0);
      asum = __builtin_amdgcn_mfma_f32_32x32x16_bf16(pa1, onesf, asum, 0, 0, 0);
      #pragma unroll
      for (int dblk = 0; dblk < 4; ++dblk){
        int d = dblk * 32 + q5;
        bf16x8 v0 = as_bf(*(const u16x8*)&Vb[d * 64 + ((4 * tp + 0 + hb) ^ (d & 7)) * 8]);
        bf16x8 v1 = as_bf(*(const u16x8*)&Vb[d * 64 + ((4 * tp + 2 + hb) ^ (d & 7)) * 8]);
        acc[dblk] = __builtin_amdgcn_mfma_f32_32x32x16_bf16(pa0, v0, acc[dblk], 0, 0, 0);
        acc[dblk] = __builtin_amdgcn_mfma_f32_32x32x16_bf16(pa1, v1, acc[dblk], 0, 0, 0);
      }
      __builtin_amdgcn_s_setprio(0);
    }
  }
  // ---- epilogue: combine tp halves in LDS (reuse K/V area), write O ----
  __syncthreads();
  float* Ls  = (float*)smem;             // [2 qw][32 q][128 d] f32 = 32KB
  float* LsS = (float*)smem + 8192;      // [2 qw][32 q] row sums
  if (tp == 1){
    #pragma unroll
    for (int dblk = 0; dblk < 4; ++dblk)
      #pragma unroll
      for (int r = 0; r < 16; ++r){
        int qrow = (r & 3) + 8 * (r >> 2) + 4 * hb;
        Ls[qw * 4096 + qrow * 128 + dblk * 32 + q5] = acc[dblk][r];
      }
    if (q5 == 0){
      #pragma unroll
      for (int r = 0; r < 16; ++r){
        int qrow = (r & 3) + 8 * (r >> 2) + 4 * hb;
        LsS[qw * 32 + qrow] = asum[r];
      }
    }
  }
  __syncthreads();
  if (tp == 0){
    #pragma unroll
    for (int r = 0; r < 16; ++r){
      int qrow = (r & 3) + 8 * (r >> 2) + 4 * hb;
      float rs = 1.0f / (asum[r] + LsS[qw * 32 + qrow]);
      int qg = qc * 64 + qw * 32 + qrow;
      #pragma unroll
      for (int dblk = 0; dblk < 4; ++dblk){
        float o = (acc[dblk][r] + Ls[qw * 4096 + qrow * 128 + dblk * 32 + q5]) * rs;
        O[(size_t)qg * 2048 + h * HD + dblk * 32 + q5] = f2bf(o);
      }
    }
  }
}

extern "C" void kernel_launch(void* const* d_in, const int* in_sizes, int n_in,
                              void* d_out, int out_size, void* d_ws, size_t ws_size,
                              hipStream_t stream){
  const int*   positions = (const int*)d_in[0];
  const float* hidden    = (const float*)d_in[1];
  const float* wq        = (const float*)d_in[2];
  const float* wk        = (const float*)d_in[3];
  const float* wv        = (const float*)d_in[4];
  const float* wo        = (const float*)d_in[5];
  const float* qw        = (const float*)d_in[6];
  const float* kw        = (const float*)d_in[7];
  float* out = (float*)d_out;

  char* ws = (char*)d_ws;
  u16* hs   = (u16*)ws; ws += (size_t)2048 * 2048 * 2;
  u16* Wqkv = (u16*)ws; ws += (size_t)4096 * 2048 * 2;   // [4096][2048] = Wq^T | Wk^T | Wv^T
  u16* Wo   = (u16*)ws; ws += (size_t)2048 * 2048 * 2;   // [2048][2048] = wo^T
  u16* QKV  = (u16*)ws; ws += (size_t)2048 * 4096 * 2;   // [T][4096]
  u16* Qr   = (u16*)ws; ws += (size_t)2048 * 2048 * 2;   // [T][16][128]
  u16* Kr   = (u16*)ws; ws += (size_t)2048 * 1024 * 2;   // [T][8][128]
  u16* Vt   = (u16*)ws; ws += (size_t)8 * 128 * 2048 * 2; // [8][128][T]
  u16* O    = (u16*)ws;                                   // [T][2048]

  cast_f32_bf16<<<2048, 256, 0, stream>>>(hidden, hs, 2048 * 2048 / 8);
  transpose_cast<<<dim3(32, 32), 256, 0, stream>>>(wq, Wqkv, 2048, 2048);
  transpose_cast<<<dim3(16, 32), 256, 0, stream>>>(wk, Wqkv + (size_t)2048 * 2048, 2048, 1024);
  transpose_cast<<<dim3(16, 32), 256, 0, stream>>>(wv, Wqkv + (size_t)3072 * 2048, 2048, 1024);
  transpose_cast<<<dim3(32, 32), 256, 0, stream>>>(wo, Wo, 2048, 2048);

  // QKV = hs @ [Wq|Wk|Wv] : M=2048, N=4096, K=2048 ; 256 blocks, 144KB LDS, 1 blk/CU
  gemm8p<false><<<dim3(16, 16, 1), 512, 147456, stream>>>(hs, Wqkv, QKV, 2048, 2048, 2048, 4096, 0);

  rmsnorm_rope<<<2048 * 24 / 4, 256, 0, stream>>>(QKV, positions, qw, kw, Qr, Kr);
  v_transpose<<<dim3(32, 2, 8), 256, 0, stream>>>(QKV, Vt);

  // attention: 512 blocks x 256 threads, 65536B LDS => 2 blocks/CU
  attn<<<dim3(32, 16), 256, 65536, stream>>>(Qr, Kr, Vt, O);

  // out = O @ wo : split-K=2 (256 blocks), fp32 partials overlay dead QKV region
  float* p0 = (float*)QKV;
  gemm8p<true><<<dim3(8, 16, 2), 512, 147456, stream>>>(O, Wo, p0, 1024, 2048, 2048, 2048,
                                                        (size_t)2048 * 2048);
  add_f32<<<4096, 256, 0, stream>>>(p0, p0 + (size_t)2048 * 2048, out, 2048 * 2048 / 4);
}